// Round 5
// baseline (360.470 us; speedup 1.0000x reference)
//
#include <hip/hip_runtime.h>
#include <stdint.h>
#include <stddef.h>

typedef __attribute__((ext_vector_type(8))) short short8;
typedef __attribute__((ext_vector_type(4))) float floatx4;
typedef __attribute__((ext_vector_type(2))) float floatx2;
typedef __attribute__((ext_vector_type(2))) unsigned int uintx2;
typedef __attribute__((ext_vector_type(4))) unsigned int uintx4;
typedef __attribute__((ext_vector_type(4))) int intx4;

#define HW_IN   4096       // 64*64
#define HW_GO   3844       // 62*62
#define OUT_ELEMS 294912   // 256*128*9
#define NCHUNK 62
#define UNITS  32

// ---- NEW ws layout (bytes), rows padded to 80 shorts (160 B), 16B chunks
//      XOR-swizzled by (row&7):
//   [0, 36569088)           : bf16-packed partials, 62*8 tiles x 18432 u32
//   [36569088, 117833728)   : GO_ws bf16 [n][i][o=256][80] (cols 62..63 = 0)
//   [117833728, 159776768)  : X_ws  bf16 [n][c=128][h=64][80]
#define PART2_OFF   0ull
#define GOWS2_OFF   36569088ull
#define XWS2_OFF    117833728ull
#define WS2_FULL    159776768ull

// ---- old fallback layout
#define PART_BYTES  73138176ull

__device__ __forceinline__ uint32_t pk_bf16(float a, float b) {
    uint32_t ua = __float_as_uint(a); ua += 0x7FFFu + ((ua >> 16) & 1u);
    uint32_t ub = __float_as_uint(b); ub += 0x7FFFu + ((ub >> 16) & 1u);
    return (ua >> 16) | (ub & 0xFFFF0000u);
}

__device__ __forceinline__ void load_lds16(const void* g, void* l) {
    __builtin_amdgcn_global_load_lds(
        (const __attribute__((address_space(1))) void*)g,
        (__attribute__((address_space(3))) void*)l, 16, 0, 0);
}

// ---- pre-pass 1: gout fp32 -> GO_ws bf16 [n][i][256][80], swizzled by o&7.
// Chunks 0..7 written (chunk 7 carries zero cols 62,63); pad chunks 8,9 unread.
__global__ __launch_bounds__(256) void go_conv2(
    const float* __restrict__ gout, uintx4* __restrict__ go_ws)
{
    const uint32_t t = blockIdx.x * 256 + threadIdx.x;  // < 4,063,232
    const uint32_t row = t >> 3, lc = t & 7;
    const uint32_t o = row & 255, ni = row >> 8;
    const uint32_t n = ni / 62, i = ni - n * 62;
    const float* g = gout + (size_t)(n * 256 + o) * HW_GO + i * 62 + lc * 8;
    uintx4 v;
    const floatx2 p0 = *(const floatx2*)g;
    const floatx2 p1 = *(const floatx2*)(g + 2);
    const floatx2 p2 = *(const floatx2*)(g + 4);
    v.x = pk_bf16(p0.x, p0.y);
    v.y = pk_bf16(p1.x, p1.y);
    v.z = pk_bf16(p2.x, p2.y);
    if (lc < 7) {
        const floatx2 p3 = *(const floatx2*)(g + 6);
        v.w = pk_bf16(p3.x, p3.y);
    } else {
        v.w = 0;   // cols 62,63: K-pad, must be zero
    }
    go_ws[row * 10 + (lc ^ (o & 7))] = v;
}

// ---- pre-pass 2: input fp32 -> X_ws bf16 [n][c][h][80], swizzled by c&7
__global__ __launch_bounds__(256) void x_conv2(
    const floatx4* __restrict__ inp, uintx4* __restrict__ x_ws)
{
    const uint32_t t = blockIdx.x * 256 + threadIdx.x;  // < 2,097,152
    const uint32_t row = t >> 3, lc = t & 7, c7 = (t >> 9) & 7;
    const floatx4 v0 = inp[row * 16 + lc * 2];
    const floatx4 v1 = inp[row * 16 + lc * 2 + 1];
    uintx4 v;
    v.x = pk_bf16(v0.x, v0.y);
    v.y = pk_bf16(v0.z, v0.w);
    v.z = pk_bf16(v1.x, v1.y);
    v.w = pk_bf16(v1.z, v1.w);
    x_ws[row * 10 + (lc ^ c7)] = v;
}

// ---- main: 512 threads = 8 waves (4 M-bands x 2 c-halves), dbuf DMA,
//      conflict-free LDS (stride 160 B + chunk XOR), shfl-derived d4.
__global__ __launch_bounds__(512, 4) void convbw4_kernel(
    const short* __restrict__ go_ws,   // [n][i][256][80]
    const short* __restrict__ x_ws,    // [n][128][64][80]
    uint32_t* __restrict__ part)       // bf16-packed partials
{
    __shared__ __align__(16) short GO_sh[2][128 * 80];  // 2 x 20480 B
    __shared__ __align__(16) short X_sh[2][96 * 80];    // 2 x 15360 B

    const int tid  = threadIdx.x;
    const int lane = tid & 63;
    const int wave = tid >> 6;          // 0..7
    const int l15  = lane & 15;
    const int quad = lane >> 4;
    const int r7   = l15 & 7;
    const int Mband = wave & 3;         // M 32-row band
    const int nih   = wave >> 2;        // c 16-half

    const int Mbase = blockIdx.x * 128;
    const int Cbase = blockIdx.y * 32;
    const int chunk = blockIdx.z;

    auto dma = [&](int u, int buf) {
        const int n_img = u / 62;
        const int i     = u - n_img * 62;
        const short* gsrc = go_ws
            + ((size_t)((n_img * 62 + i) * 256 + Mbase)) * 80;
        short* gdst = &GO_sh[buf][0];
#pragma unroll
        for (int k = wave; k < 20; k += 8)      // 20 x 1KB = 128 x 160 B
            load_lds16(gsrc + k * 512 + lane * 8, gdst + k * 512);
        short* xdst = &X_sh[buf][0];
#pragma unroll
        for (int k = wave; k < 15; k += 8) {    // 15 x 1KB = 96 x 160 B
            const int cl = k * 64 + lane;       // 16B chunk id in LDS image
            const int rowL = cl / 10, ch = cl - rowL * 10;
            const int kh = rowL >> 5, c = rowL & 31;
            const short* src = x_ws
                + ((size_t)((n_img * 128 + Cbase + c) * 64 + (i + kh))) * 80
                + ch * 8;
            load_lds16(src, xdst + k * 512);
        }
    };

    floatx4 acc[2][9];
#pragma unroll
    for (int mi = 0; mi < 2; ++mi)
#pragma unroll
        for (int t = 0; t < 9; ++t)
            acc[mi][t] = (floatx4){0.f, 0.f, 0.f, 0.f};

    dma(chunk * UNITS, 0);

#pragma unroll 1
    for (int uu = 0; uu < UNITS; ++uu) {
        __syncthreads();   // drains DMA(cur buf); prev MFMA reads done

        if (uu + 1 < UNITS) dma(chunk * UNITS + uu + 1, (uu + 1) & 1);

        const short* Gb = &GO_sh[uu & 1][0];
        const short* Xb = &X_sh[uu & 1][0];

        short8 a[2][2];
#pragma unroll
        for (int mi = 0; mi < 2; ++mi)
#pragma unroll
            for (int ks = 0; ks < 2; ++ks)
                a[mi][ks] = *(const short8*)(
                    Gb + (Mband * 32 + mi * 16 + l15) * 80
                       + (((ks * 4 + quad) ^ r7) << 3));

#pragma unroll
        for (int kh = 0; kh < 3; ++kh) {
            const short* xrow = Xb + (kh * 32 + nih * 16 + l15) * 80;
            const intx4 d0 = *(const intx4*)(xrow + ((quad ^ r7) << 3));
            const intx4 d1 = *(const intx4*)(xrow + (((quad + 4) ^ r7) << 3));
            // next-logical-chunk first dword via crossbar (no LDS banks):
            const int n0 = __shfl(d0.x, (lane + 16) & 63);
            const int n1 = __shfl(d1.x, (lane + 16) & 63);
            const int d4_0 = (quad == 3) ? n1 : n0;  // quad3: chunk4 = ks1's d.x
            const int d4_1 = n1;  // quad3 garbage -> hits A cols 62/63 == 0
#pragma unroll
            for (int ks = 0; ks < 2; ++ks) {
                const intx4 d = ks ? d1 : d0;
                const uint32_t e0 = (uint32_t)d.x, e1 = (uint32_t)d.y,
                               e2 = (uint32_t)d.z, e3 = (uint32_t)d.w,
                               e4 = (uint32_t)(ks ? d4_1 : d4_0);
                union { uint32_t u[4]; short8 s; } f0, f1, f2;
                f0.u[0] = e0; f0.u[1] = e1; f0.u[2] = e2; f0.u[3] = e3;
                f1.u[0] = (e0 >> 16) | (e1 << 16);
                f1.u[1] = (e1 >> 16) | (e2 << 16);
                f1.u[2] = (e2 >> 16) | (e3 << 16);
                f1.u[3] = (e3 >> 16) | (e4 << 16);
                f2.u[0] = e1; f2.u[1] = e2; f2.u[2] = e3; f2.u[3] = e4;
#pragma unroll
                for (int mi = 0; mi < 2; ++mi) {
                    acc[mi][kh * 3 + 0] = __builtin_amdgcn_mfma_f32_16x16x32_bf16(
                        a[mi][ks], f0.s, acc[mi][kh * 3 + 0], 0, 0, 0);
                    acc[mi][kh * 3 + 1] = __builtin_amdgcn_mfma_f32_16x16x32_bf16(
                        a[mi][ks], f1.s, acc[mi][kh * 3 + 1], 0, 0, 0);
                    acc[mi][kh * 3 + 2] = __builtin_amdgcn_mfma_f32_16x16x32_bf16(
                        a[mi][ks], f2.s, acc[mi][kh * 3 + 2], 0, 0, 0);
                }
            }
        }
    }

    // epilogue: bf16-pack r-pairs, block-local slot layout, coalesced dwords
    uint32_t* pb = part
        + (size_t)(chunk * 8 + blockIdx.x * 4 + blockIdx.y) * 18432;
#pragma unroll
    for (int mi = 0; mi < 2; ++mi)
#pragma unroll
        for (int t = 0; t < 9; ++t)
#pragma unroll
            for (int rp = 0; rp < 2; ++rp)
                pb[(uint32_t)(((mi * 9 + t) * 2 + rp) * 512 + tid)] =
                    pk_bf16(acc[mi][t][rp * 2], acc[mi][t][rp * 2 + 1]);
}

// ---- final reduce: sum 62 bf16-packed partials, unpermute to output layout
__global__ __launch_bounds__(256) void reduce2_kernel(
    const uint32_t* __restrict__ part, float* __restrict__ out)
{
    const int s = blockIdx.x * 256 + threadIdx.x;   // < 147456
    const int tile = s / 18432;
    const int slot = s - tile * 18432;
    float f0 = 0.f, f1 = 0.f;
#pragma unroll 2
    for (int z = 0; z < NCHUNK; ++z) {
        const uint32_t u = part[(size_t)(z * 8 + tile) * 18432 + slot];
        f0 += __uint_as_float(u << 16);
        f1 += __uint_as_float(u & 0xFFFF0000u);
    }
    const int j = slot >> 9, tid = slot & 511;
    const int rp = j & 1, tt = j >> 1;
    const int mi = (tt >= 9) ? 1 : 0, t = tt - 9 * mi;
    const int wv = tid >> 6, ln = tid & 63;
    const int Mband = wv & 3, nih = wv >> 2;
    const int l15 = ln & 15, quad = ln >> 4;
    const int mb = tile >> 2, cb = tile & 3;
    const int o = mb * 128 + Mband * 32 + mi * 16 + quad * 4 + rp * 2;
    const int c = cb * 32 + nih * 16 + l15;
    out[(size_t)o * 1152 + c * 9 + t] = f0;
    out[(size_t)(o + 1) * 1152 + c * 9 + t] = f1;
}

// ================= fallback (R2 path, small ws) ======
template<bool USE_ATOMIC>
__global__ __launch_bounds__(256, 1) void convbw_kernel(
    const float* __restrict__ inp, const float* __restrict__ gout,
    float* __restrict__ dst)
{
    __shared__ __align__(16) short GO_sh[128][72];
    __shared__ __align__(16) short X_sh[3][3][32][72];
    const int tid = threadIdx.x, lane = tid & 63, wave = tid >> 6;
    const int l15 = lane & 15, quad = lane >> 4;
    const int Mbase = blockIdx.x * 128, Cbase = blockIdx.y * 32;
    const int chunk = blockIdx.z;
    const int gl = tid & 31, grow0 = tid >> 5, xl = tid & 15, xrow0 = tid >> 4;
    floatx2 go_r[16];
    floatx4 x_r[6];
    auto issue_loads = [&](int u) {
        const int n_img = u / 62, i = u - n_img * 62;
        const float* bg = gout + (size_t)(n_img * 256 + Mbase) * HW_GO + i * 62;
        const float* bi = inp + (size_t)(n_img * 128 + Cbase) * HW_IN + i * 64;
#pragma unroll
        for (int p = 0; p < 16; ++p)
            go_r[p] = *(const floatx2*)(bg + (size_t)(grow0 + p * 8) * HW_GO + gl * 2);
#pragma unroll
        for (int p = 0; p < 6; ++p) {
            const int row = xrow0 + p * 16, c = row & 31, kh = row >> 5;
            x_r[p] = *(const floatx4*)(bi + (size_t)c * HW_IN + kh * 64 + xl * 4);
        }
    };
    auto flush = [&]() {
#pragma unroll
        for (int p = 0; p < 16; ++p) {
            uint32_t v = pk_bf16(go_r[p].x, go_r[p].y);
            if (gl == 31) v = 0;
            *(uint32_t*)&GO_sh[grow0 + p * 8][gl * 2] = v;
        }
#pragma unroll
        for (int p = 0; p < 6; ++p) {
            const int row = xrow0 + p * 16, c = row & 31, kh = row >> 5;
            uint32_t lo = pk_bf16(x_r[p].x, x_r[p].y);
            uint32_t hi = pk_bf16(x_r[p].z, x_r[p].w);
            uint32_t nlo = (uint32_t)__shfl((int)lo, (lane + 1) & 63);
            uintx2 v0 = {lo, hi};
            uintx2 v1 = {(lo >> 16) | (hi << 16), (hi >> 16) | (nlo << 16)};
            uintx2 v2 = {hi, nlo};
            *(uintx2*)&X_sh[kh][0][c][xl * 4] = v0;
            *(uintx2*)&X_sh[kh][1][c][xl * 4] = v1;
            *(uintx2*)&X_sh[kh][2][c][xl * 4] = v2;
        }
    };
    floatx4 acc[2][2][9];
#pragma unroll
    for (int mi = 0; mi < 2; ++mi)
#pragma unroll
        for (int ni = 0; ni < 2; ++ni)
#pragma unroll
            for (int t = 0; t < 9; ++t) acc[mi][ni][t] = (floatx4){0,0,0,0};
    issue_loads(chunk * UNITS);
#pragma unroll 1
    for (int uu = 0; uu < UNITS; ++uu) {
        flush();
        if (uu + 1 < UNITS) issue_loads(chunk * UNITS + uu + 1);
        __syncthreads();
#pragma unroll
        for (int ks = 0; ks < 2; ++ks) {
            const int kc = ks * 32 + quad * 8;
            const short8 a0 = *(const short8*)&GO_sh[wave * 32 + l15][kc];
            const short8 a1 = *(const short8*)&GO_sh[wave * 32 + 16 + l15][kc];
#pragma unroll
            for (int kh = 0; kh < 3; ++kh)
#pragma unroll
                for (int kw = 0; kw < 3; ++kw) {
                    const int t = kh * 3 + kw;
#pragma unroll
                    for (int ni = 0; ni < 2; ++ni) {
                        const short8 b = *(const short8*)&X_sh[kh][kw][ni * 16 + l15][kc];
                        acc[0][ni][t] = __builtin_amdgcn_mfma_f32_16x16x32_bf16(a0, b, acc[0][ni][t], 0, 0, 0);
                        acc[1][ni][t] = __builtin_amdgcn_mfma_f32_16x16x32_bf16(a1, b, acc[1][ni][t], 0, 0, 0);
                    }
                }
        }
        __syncthreads();
    }
    float* base = USE_ATOMIC ? dst : dst + (size_t)chunk * OUT_ELEMS;
#pragma unroll
    for (int mi = 0; mi < 2; ++mi) {
        const int o_base = Mbase + wave * 32 + mi * 16 + quad * 4;
#pragma unroll
        for (int ni = 0; ni < 2; ++ni) {
            const int c = Cbase + ni * 16 + l15;
#pragma unroll
            for (int t = 0; t < 9; ++t)
#pragma unroll
                for (int r = 0; r < 4; ++r) {
                    const size_t off = (size_t)(o_base + r) * 1152 + c * 9 + t;
                    if (USE_ATOMIC) atomicAdd(base + off, acc[mi][ni][t][r]);
                    else base[off] = acc[mi][ni][t][r];
                }
        }
    }
}

__global__ __launch_bounds__(256) void reduce_kernel(
    const floatx4* __restrict__ ws, floatx4* __restrict__ out)
{
    const int idx = blockIdx.x * 256 + threadIdx.x;
    floatx4 s = {0.f, 0.f, 0.f, 0.f};
#pragma unroll 2
    for (int ch = 0; ch < NCHUNK; ++ch)
        s += ws[(size_t)ch * (OUT_ELEMS / 4) + idx];
    out[idx] = s;
}

extern "C" void kernel_launch(void* const* d_in, const int* in_sizes, int n_in,
                              void* d_out, int out_size, void* d_ws, size_t ws_size,
                              hipStream_t stream) {
    const float* inp  = (const float*)d_in[0];
    const float* gout = (const float*)d_in[1];
    float* out = (float*)d_out;

    if (ws_size >= WS2_FULL) {
        uint32_t* part = (uint32_t*)((char*)d_ws + PART2_OFF);
        short* go_ws = (short*)((char*)d_ws + GOWS2_OFF);
        short* x_ws  = (short*)((char*)d_ws + XWS2_OFF);
        go_conv2<<<15872, 256, 0, stream>>>(gout, (uintx4*)go_ws);
        x_conv2<<<8192, 256, 0, stream>>>((const floatx4*)inp, (uintx4*)x_ws);
        dim3 grid(2, 4, NCHUNK);
        convbw4_kernel<<<grid, 512, 0, stream>>>(go_ws, x_ws, part);
        reduce2_kernel<<<576, 256, 0, stream>>>(part, out);
    } else if (ws_size >= PART_BYTES) {
        float* part = (float*)d_ws;
        dim3 grid(2, 4, NCHUNK);
        convbw_kernel<false><<<grid, 256, 0, stream>>>(inp, gout, part);
        reduce_kernel<<<OUT_ELEMS / 4 / 256, 256, 0, stream>>>(
            (const floatx4*)part, (floatx4*)out);
    } else {
        hipMemsetAsync(d_out, 0, (size_t)out_size * sizeof(float), stream);
        dim3 grid(2, 4, NCHUNK);
        convbw_kernel<true><<<grid, 256, 0, stream>>>(inp, gout, out);
    }
}